// Round 13
// baseline (129.651 us; speedup 1.0000x reference)
//
#include <hip/hip_runtime.h>

typedef _Float16 half4_t __attribute__((ext_vector_type(4)));
typedef _Float16 half8_t __attribute__((ext_vector_type(8)));
typedef float f32x4 __attribute__((ext_vector_type(4)));

constexpr int NX = 256, NU = 32, NY = 32, BATCH = 16, T = 8192;
constexpr int NC = 64, L = 128;       // 64 chunks of 128 steps -> grid 1024
constexpr int SUBT = 32, NSUB = L / SUBT;   // 4 subtiles
constexpr int ZP = 264;               // zt pitch (halves)

__device__ __forceinline__ half8_t cvt8(float4 a, float4 b) {
    half8_t h;
    h[0] = (_Float16)a.x; h[1] = (_Float16)a.y; h[2] = (_Float16)a.z; h[3] = (_Float16)a.w;
    h[4] = (_Float16)b.x; h[5] = (_Float16)b.y; h[6] = (_Float16)b.z; h[7] = (_Float16)b.w;
    return h;
}

// ---------- pre: Bzh=(Q^T Bm) f16, z0=x0 Q f32 ; split-K x4 ----------
__global__ __launch_bounds__(256) void k_pre(
    const float* __restrict__ x0, const float* __restrict__ Q,
    const float* __restrict__ Bm,
    _Float16* __restrict__ Bzh, float* __restrict__ z0)
{
    int o = blockIdx.x * 64 + (threadIdx.x >> 2);
    int p = threadIdx.x & 3;
    if (o >= 12288) return;
    float s = 0.f;
    int k0 = p * 64;
    if (o < 8192) {                                     // Bzh[n][j] = sum_k Q[k][n] Bm[k][j]
        int n = o >> 5, j = o & 31;
        for (int k = k0; k < k0 + 64; ++k) s = fmaf(Q[k * NX + n], Bm[k * NU + j], s);
    } else {                                            // z0[b][nn] = sum_k x0[b][k] Q[k][nn]
        int g = o - 8192; int b = g >> 8, nn = g & 255;
        for (int k = k0; k < k0 + 64; ++k) s = fmaf(x0[b * NX + k], Q[k * NX + nn], s);
    }
    s += __shfl_xor(s, 1);
    s += __shfl_xor(s, 2);
    if (p == 0) {
        if (o < 8192) Bzh[o] = (_Float16)s;
        else          z0[o - 8192] = s;
    }
}

// ---------- phase 1: direct-load v-MFMA, weighted reduction -> chunk end S (no LDS) ----------
__global__ __launch_bounds__(256) void k_phase1(
    const float* __restrict__ u, const float* __restrict__ lam,
    const _Float16* __restrict__ Bzh, float* __restrict__ S)
{
    const int b = blockIdx.x >> 6, c = blockIdx.x & 63, tid = threadIdx.x;
    const int w = tid >> 6, lane = tid & 63, m16 = lane & 15, quad = lane >> 4;

    const float* ug = u + ((size_t)(b * T) + (size_t)c * L) * NU;
    const float* r0 = ug + (size_t)m16 * NU + quad * 8;
    const float* r1 = ug + (size_t)(16 + m16) * NU + quad * 8;

    // preload sub 0 fragments (f32)
    float4 c0a = *(const float4*)r0, c0b = *(const float4*)(r0 + 4);
    float4 c1a = *(const float4*)r1, c1b = *(const float4*)(r1 + 4);

    half8_t bfrag[4];
    #pragma unroll
    for (int i = 0; i < 4; ++i)
        bfrag[i] = *(const half8_t*)&Bzh[((4 * w + i) * 16 + m16) * NU + quad * 8];

    float wr[4][4], wt16[4], l32[4], acc[4];
    #pragma unroll
    for (int i = 0; i < 4; ++i) {
        float la = lam[(4 * w + i) * 16 + m16];
        float p2 = la * la, p4 = p2 * p2, p8 = p4 * p4, p16 = p8 * p8;
        float inv1 = 1.0f / la;
        float inv4 = (inv1 * inv1) * (inv1 * inv1);
        float pq = 1.0f;
        if (quad & 1) pq *= inv4;
        if (quad & 2) pq *= inv4 * inv4;
        float w0 = (p16 * p8 * p4 * p2 * la) * pq;      // lam^(31-4q)
        wr[i][0] = w0;
        wr[i][1] = w0 * inv1;
        wr[i][2] = wr[i][1] * inv1;
        wr[i][3] = wr[i][2] * inv1;
        wt16[i] = 1.0f / p16;                            // lam^-16
        l32[i] = p16 * p16;                              // lam^32
        acc[i] = 0.f;
    }

    for (int sub = 0; sub < NSUB; ++sub) {
        half8_t af0 = cvt8(c0a, c0b);
        half8_t af1 = cvt8(c1a, c1b);
        if (sub < NSUB - 1) {                            // prefetch next subtile
            const float* n0 = r0 + (size_t)(sub + 1) * SUBT * NU;
            const float* n1 = r1 + (size_t)(sub + 1) * SUBT * NU;
            c0a = *(const float4*)n0; c0b = *(const float4*)(n0 + 4);
            c1a = *(const float4*)n1; c1b = *(const float4*)(n1 + 4);
        }
        #pragma unroll
        for (int i = 0; i < 4; ++i) {
            f32x4 z4 = {0.f, 0.f, 0.f, 0.f};
            f32x4 v0 = __builtin_amdgcn_mfma_f32_16x16x32_f16(af0, bfrag[i], z4, 0, 0, 0);
            f32x4 v1 = __builtin_amdgcn_mfma_f32_16x16x32_f16(af1, bfrag[i], z4, 0, 0, 0);
            float s0 = wr[i][0] * v0[0] + wr[i][1] * v0[1] + wr[i][2] * v0[2] + wr[i][3] * v0[3];
            float s1 = wr[i][0] * v1[0] + wr[i][1] * v1[1] + wr[i][2] * v1[2] + wr[i][3] * v1[3];
            acc[i] = fmaf(l32[i], acc[i], fmaf(wt16[i], s1, s0));
        }
    }
    #pragma unroll
    for (int i = 0; i < 4; ++i) {
        acc[i] += __shfl_xor(acc[i], 16);
        acc[i] += __shfl_xor(acc[i], 32);
    }
    float out = quad == 0 ? acc[0] : quad == 1 ? acc[1] : quad == 2 ? acc[2] : acc[3];
    S[(size_t)blockIdx.x * NX + (4 * w + quad) * 16 + m16] = out;
}

// ---------- phase 3: prefix -> direct-load scan -> proj MFMA -> f4 store ----------
__global__ __launch_bounds__(256) void k_phase3(
    const float* __restrict__ u, const float* __restrict__ lam,
    const _Float16* __restrict__ Bzh, const float* __restrict__ Q,
    const float* __restrict__ D, const float* __restrict__ S,
    const float* __restrict__ z0, float* __restrict__ y)
{
    __shared__ __align__(16) _Float16 zt[SUBT][ZP];     // 16.5 KB
    __shared__ float pvec[NX];                          // 1 KB

    const int b = blockIdx.x >> 6, c = blockIdx.x & 63, tid = threadIdx.x;
    const int w = tid >> 6, lane = tid & 63, m16 = lane & 15, quad = lane >> 4;
    const int tw = w & 1, yw = w >> 1;                  // proj: t-tile, y-tile

    const float* ug = u + ((size_t)(b * T) + (size_t)c * L) * NU;
    const float* r0 = ug + (size_t)m16 * NU + quad * 8;
    const float* r1 = ug + (size_t)(16 + m16) * NU + quad * 8;

    // preload sub 0 fragments (overlaps prefix)
    float4 c0a = *(const float4*)r0, c0b = *(const float4*)(r0 + 4);
    float4 c1a = *(const float4*)r1, c1b = *(const float4*)(r1 + 4);

    // ---- prefix: pvec[n] = sum_k lamL^k S[b, c-1-k, n] + lamL^c z0[b, n] ----
    {
        float la = lam[tid];
        float l2L = 128.0f * __log2f(la);               // log2(lam^128)
        const float* Sb = S + (size_t)(b * NC) * NX + tid;
        float pv = 0.f;
        #pragma unroll 8
        for (int k = 0; k < c; ++k) {
            float wgt = exp2f((float)k * l2L);
            pv = fmaf(wgt, Sb[(size_t)(c - 1 - k) * NX], pv);
        }
        pvec[tid] = fmaf(exp2f((float)c * l2L), z0[b * NX + tid], pv);
    }

    half8_t bfrag[4];
    #pragma unroll
    for (int i = 0; i < 4; ++i)
        bfrag[i] = *(const half8_t*)&Bzh[((4 * w + i) * 16 + m16) * NU + quad * 8];
    half8_t wfrag[9];                                   // W = [Q rows 0..31 | D], f16 cast
    #pragma unroll
    for (int kk = 0; kk < 8; ++kk) {
        float4 qa = *(const float4*)&Q[(size_t)(yw * 16 + m16) * NX + kk * 32 + quad * 8];
        float4 qb = *(const float4*)&Q[(size_t)(yw * 16 + m16) * NX + kk * 32 + quad * 8 + 4];
        wfrag[kk] = cvt8(qa, qb);
    }
    {
        float4 da = *(const float4*)&D[(size_t)(yw * 16 + m16) * NU + quad * 8];
        float4 db = *(const float4*)&D[(size_t)(yw * 16 + m16) * NU + quad * 8 + 4];
        wfrag[8] = cvt8(da, db);
    }

    // per-col lambda powers
    float lamn[4], inv1[4], iq[4], i16p[4], fq[4], f16p[4], l32[4], p[4];
    #pragma unroll
    for (int i = 0; i < 4; ++i) {
        int ni = (4 * w + i) * 16 + m16;
        float la = lam[ni];
        lamn[i] = la;
        float p2 = la * la, p4 = p2 * p2, p8 = p4 * p4, p16 = p8 * p8;
        float iv = 1.0f / la;
        inv1[i] = iv;
        float iv4 = (iv * iv) * (iv * iv);
        float pqi = 1.0f, pqf = 1.0f;
        if (quad & 1) { pqi *= iv4; pqf *= p4; }
        if (quad & 2) { pqi *= iv4 * iv4; pqf *= p8; }
        iq[i] = iv * pqi;                               // lam^-(1+4q)
        fq[i] = pqf;                                    // lam^(4q)
        i16p[i] = 1.0f / p16;
        f16p[i] = p16;
        l32[i] = p16 * p16;
    }
    __syncthreads();                                    // pvec ready
    #pragma unroll
    for (int i = 0; i < 4; ++i)
        p[i] = pvec[(4 * w + i) * 16 + m16];

    float* yg = y + ((size_t)(b * T) + (size_t)c * L) * NY;

    for (int sub = 0; sub < NSUB; ++sub) {
        half8_t af0 = cvt8(c0a, c0b);
        half8_t af1 = cvt8(c1a, c1b);
        if (sub < NSUB - 1) {                            // prefetch next subtile
            const float* n0 = r0 + (size_t)(sub + 1) * SUBT * NU;
            const float* n1 = r1 + (size_t)(sub + 1) * SUBT * NU;
            c0a = *(const float4*)n0; c0b = *(const float4*)(n0 + 4);
            c1a = *(const float4*)n1; c1b = *(const float4*)(n1 + 4);
        }
        // v = u @ Bz^T ; V'[s] = lam^-(1+s) v_s ; exclusive prefix via shuffles
        #pragma unroll
        for (int i = 0; i < 4; ++i) {
            int ni = (4 * w + i) * 16 + m16;
            f32x4 z4 = {0.f, 0.f, 0.f, 0.f};
            f32x4 v0 = __builtin_amdgcn_mfma_f32_16x16x32_f16(af0, bfrag[i], z4, 0, 0, 0);
            f32x4 v1 = __builtin_amdgcn_mfma_f32_16x16x32_f16(af1, bfrag[i], z4, 0, 0, 0);
            float a0[4], a1[4];
            float sc = iq[i];
            #pragma unroll
            for (int r = 0; r < 4; ++r) {
                a0[r] = v0[r] * sc;
                a1[r] = v1[r] * (sc * i16p[i]);
                sc *= inv1[i];
            }
            float e0[4], e1[4];
            e0[0] = 0.f; e0[1] = a0[0]; e0[2] = e0[1] + a0[1]; e0[3] = e0[2] + a0[2];
            float S40 = e0[3] + a0[3];
            e1[0] = 0.f; e1[1] = a1[0]; e1[2] = e1[1] + a1[1]; e1[3] = e1[2] + a1[2];
            float S41 = e1[3] + a1[3];
            float incl0 = S40;
            float t0 = __shfl_up(incl0, 16); if (quad >= 1) incl0 += t0;
            t0 = __shfl_up(incl0, 32);       if (quad >= 2) incl0 += t0;
            float excl0 = incl0 - S40;
            float total0 = __shfl(incl0, 48 + m16);
            float incl1 = S41;
            float t1 = __shfl_up(incl1, 16); if (quad >= 1) incl1 += t1;
            t1 = __shfl_up(incl1, 32);       if (quad >= 2) incl1 += t1;
            float excl1 = incl1 - S41;
            float total1 = __shfl(incl1, 48 + m16);
            float f = fq[i];
            #pragma unroll
            for (int r = 0; r < 4; ++r) {
                float zv0 = f * (p[i] + (excl0 + e0[r]));
                float zv1 = (f * f16p[i]) * (p[i] + (total0 + excl1 + e1[r]));
                zt[quad * 4 + r][ni] = (_Float16)zv0;
                zt[16 + quad * 4 + r][ni] = (_Float16)zv1;
                f *= lamn[i];
            }
            p[i] = l32[i] * (p[i] + (total0 + total1));
        }
        __syncthreads();                                 // zt ready

        // y^T tile: A = W rows, B = zt columns / u fragment (registers)
        f32x4 acc = {0.f, 0.f, 0.f, 0.f};
        #pragma unroll
        for (int kk = 0; kk < 8; ++kk) {
            half8_t az = *(const half8_t*)&zt[tw * 16 + m16][kk * 32 + quad * 8];
            acc = __builtin_amdgcn_mfma_f32_16x16x32_f16(wfrag[kk], az, acc, 0, 0, 0);
        }
        {
            half8_t au = tw ? af1 : af0;                 // u rows tw*16+m16 (registers)
            acc = __builtin_amdgcn_mfma_f32_16x16x32_f16(wfrag[8], au, acc, 0, 0, 0);
        }
        {   // lane: t = tw*16+m16, y = yw*16 + quad*4 + r -> one aligned float4
            float4 v = make_float4(acc[0], acc[1], acc[2], acc[3]);
            *(float4*)&yg[(size_t)(sub * SUBT + tw * 16 + m16) * NY + yw * 16 + quad * 4] = v;
        }
        if (sub < NSUB - 1)
            __syncthreads();                             // zt reads done before next scan
    }
}

extern "C" void kernel_launch(void* const* d_in, const int* in_sizes, int n_in,
                              void* d_out, int out_size, void* d_ws, size_t ws_size,
                              hipStream_t stream) {
    (void)in_sizes; (void)n_in; (void)out_size; (void)ws_size;
    const float* x0  = (const float*)d_in[0];
    const float* u   = (const float*)d_in[1];
    const float* Q   = (const float*)d_in[2];
    const float* lam = (const float*)d_in[3];
    const float* Bm  = (const float*)d_in[4];
    const float* D   = (const float*)d_in[6];
    float* y = (float*)d_out;

    char* ws = (char*)d_ws;
    _Float16* Bzh = (_Float16*)(ws);                    // 16384 B
    float*    z0  = (float*)(ws + 16384);               // 16384 B
    float*    S   = (float*)(ws + 32768);               // 1 MB

    k_pre   <<<192, 256, 0, stream>>>(x0, Q, Bm, Bzh, z0);
    k_phase1<<<BATCH * NC, 256, 0, stream>>>(u, lam, Bzh, S);
    k_phase3<<<BATCH * NC, 256, 0, stream>>>(u, lam, Bzh, Q, D, S, z0, y);
}

// Round 14
// 114.217 us; speedup vs baseline: 1.1351x; 1.1351x over previous
//
#include <hip/hip_runtime.h>

typedef _Float16 half4_t __attribute__((ext_vector_type(4)));
typedef _Float16 half8_t __attribute__((ext_vector_type(8)));
typedef float f32x4 __attribute__((ext_vector_type(4)));

constexpr int NX = 256, NU = 32, NY = 32, BATCH = 16, T = 8192;
constexpr int NC = 64, L = 128;       // 64 chunks of 128 steps
constexpr int SUBT = 32, NSUB = L / SUBT;   // 4 subtiles
constexpr int ZP = 264;               // zt pitch (halves)

__device__ __forceinline__ half8_t cvt8(float4 a, float4 b) {
    half8_t h;
    h[0] = (_Float16)a.x; h[1] = (_Float16)a.y; h[2] = (_Float16)a.z; h[3] = (_Float16)a.w;
    h[4] = (_Float16)b.x; h[5] = (_Float16)b.y; h[6] = (_Float16)b.z; h[7] = (_Float16)b.w;
    return h;
}

// ---------- pre: Bzh=(Q^T Bm) f16, z0=x0 Q f32 ; split-K x4 ----------
__global__ __launch_bounds__(256) void k_pre(
    const float* __restrict__ x0, const float* __restrict__ Q,
    const float* __restrict__ Bm,
    _Float16* __restrict__ Bzh, float* __restrict__ z0)
{
    int o = blockIdx.x * 64 + (threadIdx.x >> 2);
    int p = threadIdx.x & 3;
    if (o >= 12288) return;
    float s = 0.f;
    int k0 = p * 64;
    if (o < 8192) {                                     // Bzh[n][j] = sum_k Q[k][n] Bm[k][j]
        int n = o >> 5, j = o & 31;
        for (int k = k0; k < k0 + 64; ++k) s = fmaf(Q[k * NX + n], Bm[k * NU + j], s);
    } else {                                            // z0[b][nn] = sum_k x0[b][k] Q[k][nn]
        int g = o - 8192; int b = g >> 8, nn = g & 255;
        for (int k = k0; k < k0 + 64; ++k) s = fmaf(x0[b * NX + k], Q[k * NX + nn], s);
    }
    s += __shfl_xor(s, 1);
    s += __shfl_xor(s, 2);
    if (p == 0) {
        if (o < 8192) Bzh[o] = (_Float16)s;
        else          z0[o - 8192] = s;
    }
}

// ---------- phase 1: v via MFMA, weighted-sum reduction -> chunk end state S ----------
__global__ __launch_bounds__(256) void k_phase1(
    const float* __restrict__ u, const float* __restrict__ lam,
    const _Float16* __restrict__ Bzh, float* __restrict__ S)
{
    __shared__ __align__(16) _Float16 ut[2][SUBT][32];  // swizzled, double-buffered

    const int b = blockIdx.x >> 6, c = blockIdx.x & 63, tid = threadIdx.x;
    const int w = tid >> 6, lane = tid & 63, m16 = lane & 15, quad = lane >> 4;

    half8_t bfrag[4];
    #pragma unroll
    for (int i = 0; i < 4; ++i)
        bfrag[i] = *(const half8_t*)&Bzh[((4 * w + i) * 16 + m16) * NU + quad * 8];

    float wr[4][4], wt16[4], l32[4], acc[4];
    #pragma unroll
    for (int i = 0; i < 4; ++i) {
        float la = lam[(4 * w + i) * 16 + m16];
        float p2 = la * la, p4 = p2 * p2, p8 = p4 * p4, p16 = p8 * p8;
        float inv1 = 1.0f / la;
        float inv4 = (inv1 * inv1) * (inv1 * inv1);
        float pq = 1.0f;
        if (quad & 1) pq *= inv4;
        if (quad & 2) pq *= inv4 * inv4;
        float w0 = (p16 * p8 * p4 * p2 * la) * pq;      // lam^(31-4q)
        wr[i][0] = w0;
        wr[i][1] = w0 * inv1;
        wr[i][2] = wr[i][1] * inv1;
        wr[i][3] = wr[i][2] * inv1;
        wt16[i] = 1.0f / p16;                            // lam^-16
        l32[i] = p16 * p16;                              // lam^32
        acc[i] = 0.f;
    }

    const float* ug = u + ((size_t)(b * T) + (size_t)c * L) * NU;

    for (int sub = 0; sub < NSUB; ++sub) {
        {   // stage u tile (32t x 32j) f16, swizzled: col' = (col + (t&3)*8) & 31
            float4 uu = *(const float4*)(ug + (size_t)sub * SUBT * NU + tid * 4);
            int tr = tid >> 3, cb = ((tid & 7) * 4 + (tr & 3) * 8) & 31;
            half4_t h; h.x = (_Float16)uu.x; h.y = (_Float16)uu.y;
            h.z = (_Float16)uu.z; h.w = (_Float16)uu.w;
            *(half4_t*)&ut[sub & 1][tr][cb] = h;
        }
        __syncthreads();
        int rot = (m16 & 3) * 8;
        half8_t af0 = *(const half8_t*)&ut[sub & 1][m16][(quad * 8 + rot) & 31];
        half8_t af1 = *(const half8_t*)&ut[sub & 1][16 + m16][(quad * 8 + rot) & 31];
        #pragma unroll
        for (int i = 0; i < 4; ++i) {
            f32x4 z4 = {0.f, 0.f, 0.f, 0.f};
            f32x4 v0 = __builtin_amdgcn_mfma_f32_16x16x32_f16(af0, bfrag[i], z4, 0, 0, 0);
            f32x4 v1 = __builtin_amdgcn_mfma_f32_16x16x32_f16(af1, bfrag[i], z4, 0, 0, 0);
            float s0 = wr[i][0] * v0[0] + wr[i][1] * v0[1] + wr[i][2] * v0[2] + wr[i][3] * v0[3];
            float s1 = wr[i][0] * v1[0] + wr[i][1] * v1[1] + wr[i][2] * v1[2] + wr[i][3] * v1[3];
            acc[i] = fmaf(l32[i], acc[i], fmaf(wt16[i], s1, s0));
        }
    }
    #pragma unroll
    for (int i = 0; i < 4; ++i) {
        acc[i] += __shfl_xor(acc[i], 16);
        acc[i] += __shfl_xor(acc[i], 32);
    }
    float out = quad == 0 ? acc[0] : quad == 1 ? acc[1] : quad == 2 ? acc[2] : acc[3];
    S[(size_t)blockIdx.x * NX + (4 * w + quad) * 16 + m16] = out;
}

// ---------- phase 3: two chunk-streams per block, 1 barrier per subtile-chunk ----------
__global__ __launch_bounds__(256) void k_phase3(
    const float* __restrict__ u, const float* __restrict__ lam,
    const _Float16* __restrict__ Bzh, const float* __restrict__ Q,
    const float* __restrict__ D, const float* __restrict__ S,
    const float* __restrict__ z0, float* __restrict__ y)
{
    __shared__ __align__(16) _Float16 ut[2][2][SUBT][32];   // [stream][dbuf] 8 KB
    __shared__ __align__(16) _Float16 zt[2][SUBT][ZP];      // [stream] 33 KB
    __shared__ float pvec[2][NX];                           // 2 KB

    const int bx = blockIdx.x, b = bx >> 5, ci = bx & 31, tid = threadIdx.x;
    const int cA = 2 * ci, cB = 2 * ci + 1;
    const int w = tid >> 6, lane = tid & 63, m16 = lane & 15, quad = lane >> 4;
    const int tw = w & 1, yw = w >> 1;                  // proj: t-tile, y-tile
    const int rot = (m16 & 3) * 8;
    const int tr = tid >> 3, cb = ((tid & 7) * 4 + (tr & 3) * 8) & 31;

    const float* ugA = u + ((size_t)(b * T) + (size_t)cA * L) * NU;
    const float* ugB = u + ((size_t)(b * T) + (size_t)cB * L) * NU;
    float4 ucA = *(const float4*)(ugA + tid * 4);       // sub 0 loads (overlap prefix)
    float4 ucB = *(const float4*)(ugB + tid * 4);

    // ---- prefix: stream A by weighted sum; stream B = lamL*A + S[cA] ----
    {
        float la = lam[tid];
        float l2L = 128.0f * __log2f(la);               // log2(lam^128)
        const float* Sb = S + (size_t)(b * NC) * NX + tid;
        float pv = 0.f;
        #pragma unroll 8
        for (int k = 0; k < cA; ++k) {
            float wgt = exp2f((float)k * l2L);
            pv = fmaf(wgt, Sb[(size_t)(cA - 1 - k) * NX], pv);
        }
        float pA = fmaf(exp2f((float)cA * l2L), z0[b * NX + tid], pv);
        pvec[0][tid] = pA;
        pvec[1][tid] = fmaf(exp2f(l2L), pA, Sb[(size_t)cA * NX]);
    }

    half8_t bfrag[4];
    #pragma unroll
    for (int i = 0; i < 4; ++i)
        bfrag[i] = *(const half8_t*)&Bzh[((4 * w + i) * 16 + m16) * NU + quad * 8];
    half8_t wfrag[9];                                   // W = [Q rows 0..31 | D]
    #pragma unroll
    for (int kk = 0; kk < 8; ++kk) {
        float4 qa = *(const float4*)&Q[(size_t)(yw * 16 + m16) * NX + kk * 32 + quad * 8];
        float4 qb = *(const float4*)&Q[(size_t)(yw * 16 + m16) * NX + kk * 32 + quad * 8 + 4];
        wfrag[kk] = cvt8(qa, qb);
    }
    {
        float4 da = *(const float4*)&D[(size_t)(yw * 16 + m16) * NU + quad * 8];
        float4 db = *(const float4*)&D[(size_t)(yw * 16 + m16) * NU + quad * 8 + 4];
        wfrag[8] = cvt8(da, db);
    }

    // per-col lambda powers (shared by both streams)
    float lamn[4], inv1[4], iq[4], i16p[4], fq[4], f16p[4], l32[4], pA[4], pB[4];
    #pragma unroll
    for (int i = 0; i < 4; ++i) {
        int ni = (4 * w + i) * 16 + m16;
        float la = lam[ni];
        lamn[i] = la;
        float p2 = la * la, p4 = p2 * p2, p8 = p4 * p4, p16 = p8 * p8;
        float iv = 1.0f / la;
        inv1[i] = iv;
        float iv4 = (iv * iv) * (iv * iv);
        float pqi = 1.0f, pqf = 1.0f;
        if (quad & 1) { pqi *= iv4; pqf *= p4; }
        if (quad & 2) { pqi *= iv4 * iv4; pqf *= p8; }
        iq[i] = iv * pqi;                               // lam^-(1+4q)
        fq[i] = pqf;                                    // lam^(4q)
        i16p[i] = 1.0f / p16;
        f16p[i] = p16;
        l32[i] = p16 * p16;
    }

    {   // stage sub 0, both streams
        half4_t hA; hA.x = (_Float16)ucA.x; hA.y = (_Float16)ucA.y;
        hA.z = (_Float16)ucA.z; hA.w = (_Float16)ucA.w;
        *(half4_t*)&ut[0][0][tr][cb] = hA;
        half4_t hB; hB.x = (_Float16)ucB.x; hB.y = (_Float16)ucB.y;
        hB.z = (_Float16)ucB.z; hB.w = (_Float16)ucB.w;
        *(half4_t*)&ut[1][0][tr][cb] = hB;
    }
    __syncthreads();                                    // pvec + ut[*][0] ready
    #pragma unroll
    for (int i = 0; i < 4; ++i) {
        pA[i] = pvec[0][(4 * w + i) * 16 + m16];
        pB[i] = pvec[1][(4 * w + i) * 16 + m16];
    }
    float4 unA = *(const float4*)(ugA + (size_t)SUBT * NU + tid * 4);   // sub 1
    float4 unB = *(const float4*)(ugB + (size_t)SUBT * NU + tid * 4);

    float* ygA = y + ((size_t)(b * T) + (size_t)cA * L) * NY;
    float* ygB = y + ((size_t)(b * T) + (size_t)cB * L) * NY;

    half8_t afA0, afA1, afB0, afB1;

    for (int sub = 0; sub < NSUB; ++sub) {
        // ---- scan both streams: read ut[s][sub&1], write zt[s] ----
        afA0 = *(const half8_t*)&ut[0][sub & 1][m16][(quad * 8 + rot) & 31];
        afA1 = *(const half8_t*)&ut[0][sub & 1][16 + m16][(quad * 8 + rot) & 31];
        afB0 = *(const half8_t*)&ut[1][sub & 1][m16][(quad * 8 + rot) & 31];
        afB1 = *(const half8_t*)&ut[1][sub & 1][16 + m16][(quad * 8 + rot) & 31];
        if (sub < NSUB - 2) {   // issue loads for sub+2
            ucA = *(const float4*)(ugA + (size_t)(sub + 2) * SUBT * NU + tid * 4);
            ucB = *(const float4*)(ugB + (size_t)(sub + 2) * SUBT * NU + tid * 4);
        }
        #pragma unroll
        for (int st = 0; st < 2; ++st) {
            half8_t af0 = st ? afB0 : afA0;
            half8_t af1 = st ? afB1 : afA1;
            float*  pp  = st ? pB : pA;
            #pragma unroll
            for (int i = 0; i < 4; ++i) {
                int ni = (4 * w + i) * 16 + m16;
                f32x4 z4 = {0.f, 0.f, 0.f, 0.f};
                f32x4 v0 = __builtin_amdgcn_mfma_f32_16x16x32_f16(af0, bfrag[i], z4, 0, 0, 0);
                f32x4 v1 = __builtin_amdgcn_mfma_f32_16x16x32_f16(af1, bfrag[i], z4, 0, 0, 0);
                float a0[4], a1[4];
                float sc = iq[i];
                #pragma unroll
                for (int r = 0; r < 4; ++r) {
                    a0[r] = v0[r] * sc;
                    a1[r] = v1[r] * (sc * i16p[i]);
                    sc *= inv1[i];
                }
                float e0[4], e1[4];
                e0[0] = 0.f; e0[1] = a0[0]; e0[2] = e0[1] + a0[1]; e0[3] = e0[2] + a0[2];
                float S40 = e0[3] + a0[3];
                e1[0] = 0.f; e1[1] = a1[0]; e1[2] = e1[1] + a1[1]; e1[3] = e1[2] + a1[2];
                float S41 = e1[3] + a1[3];
                float incl0 = S40;
                float t0 = __shfl_up(incl0, 16); if (quad >= 1) incl0 += t0;
                t0 = __shfl_up(incl0, 32);       if (quad >= 2) incl0 += t0;
                float excl0 = incl0 - S40;
                float total0 = __shfl(incl0, 48 + m16);
                float incl1 = S41;
                float t1 = __shfl_up(incl1, 16); if (quad >= 1) incl1 += t1;
                t1 = __shfl_up(incl1, 32);       if (quad >= 2) incl1 += t1;
                float excl1 = incl1 - S41;
                float total1 = __shfl(incl1, 48 + m16);
                float f = fq[i];
                #pragma unroll
                for (int r = 0; r < 4; ++r) {
                    float zv0 = f * (pp[i] + (excl0 + e0[r]));
                    float zv1 = (f * f16p[i]) * (pp[i] + (total0 + excl1 + e1[r]));
                    zt[st][quad * 4 + r][ni] = (_Float16)zv0;
                    zt[st][16 + quad * 4 + r][ni] = (_Float16)zv1;
                    f *= lamn[i];
                }
                pp[i] = l32[i] * (pp[i] + (total0 + total1));
            }
        }
        // ---- stage(sub+1) both streams into the other ut buffer ----
        if (sub < NSUB - 1) {
            half4_t hA; hA.x = (_Float16)unA.x; hA.y = (_Float16)unA.y;
            hA.z = (_Float16)unA.z; hA.w = (_Float16)unA.w;
            *(half4_t*)&ut[0][(sub + 1) & 1][tr][cb] = hA;
            half4_t hB; hB.x = (_Float16)unB.x; hB.y = (_Float16)unB.y;
            hB.z = (_Float16)unB.z; hB.w = (_Float16)unB.w;
            *(half4_t*)&ut[1][(sub + 1) & 1][tr][cb] = hB;
            unA = ucA; unB = ucB;
        }
        __syncthreads();                                 // zt + ut(sub+1) ready

        // ---- proj both streams: read zt[s] + registers ----
        #pragma unroll
        for (int st = 0; st < 2; ++st) {
            f32x4 acc = {0.f, 0.f, 0.f, 0.f};
            #pragma unroll
            for (int kk = 0; kk < 8; ++kk) {
                half8_t az = *(const half8_t*)&zt[st][tw * 16 + m16][kk * 32 + quad * 8];
                acc = __builtin_amdgcn_mfma_f32_16x16x32_f16(wfrag[kk], az, acc, 0, 0, 0);
            }
            {
                half8_t au = st ? (tw ? afB1 : afB0) : (tw ? afA1 : afA0);
                acc = __builtin_amdgcn_mfma_f32_16x16x32_f16(wfrag[8], au, acc, 0, 0, 0);
            }
            float* yg = st ? ygB : ygA;
            float4 v = make_float4(acc[0], acc[1], acc[2], acc[3]);
            *(float4*)&yg[(size_t)(sub * SUBT + tw * 16 + m16) * NY + yw * 16 + quad * 4] = v;
        }
        if (sub < NSUB - 1)
            __syncthreads();                             // zt reads done before next scan
    }
}

extern "C" void kernel_launch(void* const* d_in, const int* in_sizes, int n_in,
                              void* d_out, int out_size, void* d_ws, size_t ws_size,
                              hipStream_t stream) {
    (void)in_sizes; (void)n_in; (void)out_size; (void)ws_size;
    const float* x0  = (const float*)d_in[0];
    const float* u   = (const float*)d_in[1];
    const float* Q   = (const float*)d_in[2];
    const float* lam = (const float*)d_in[3];
    const float* Bm  = (const float*)d_in[4];
    const float* D   = (const float*)d_in[6];
    float* y = (float*)d_out;

    char* ws = (char*)d_ws;
    _Float16* Bzh = (_Float16*)(ws);                    // 16384 B
    float*    z0  = (float*)(ws + 16384);               // 16384 B
    float*    S   = (float*)(ws + 32768);               // 1 MB

    k_pre   <<<192, 256, 0, stream>>>(x0, Q, Bm, Bzh, z0);
    k_phase1<<<BATCH * NC, 256, 0, stream>>>(u, lam, Bzh, S);
    k_phase3<<<BATCH * NC / 2, 256, 0, stream>>>(u, lam, Bzh, Q, D, S, z0, y);
}